// Round 4
// baseline (174.932 us; speedup 1.0000x reference)
//
#include <hip/hip_runtime.h>

// SparseMoE: T=4096, D=1024, E=8, H=2048, top_k=2.
// R4: double-buffered LDS + prefetch-1 (T3 minimal 2-phase): STAGE(next)
// issued BEFORE compute(cur); single vmcnt(0)-drain barrier per K-tile so
// global_load_lds latency hides under the 32-MFMA phase. convert_x fused
// into gate_kernel. Swizzled LDS (0 bank conflicts) + atomic scatter kept.

#define NTOK 4096
#define DIM  1024
#define NEXP 8
#define HID  2048

#define BM 128
#define BN 128
#define BK 64

using u16    = unsigned short;
using u16x4  = __attribute__((ext_vector_type(4))) unsigned short;
using u16x8  = __attribute__((ext_vector_type(8))) unsigned short;
using bf16x8 = __attribute__((ext_vector_type(8))) __bf16;
using f32x4  = __attribute__((ext_vector_type(4))) float;

typedef const __attribute__((address_space(1))) unsigned char* gas1p;
typedef __attribute__((address_space(3))) unsigned char* gas3p;

__device__ __forceinline__ void gload16(void* lds, const void* g) {
  __builtin_amdgcn_global_load_lds((gas1p)g, (gas3p)lds, 16, 0, 0);
}

__device__ inline u16 f2bf(float f) {
  union { float f; unsigned u; } v; v.f = f;
  unsigned r = v.u + 0x7fffu + ((v.u >> 16) & 1u);  // RNE, no NaN in this data
  return (u16)(r >> 16);
}

// ---------------- fp32 -> bf16 bulk convert (8 elems/thread) -----------------
__global__ __launch_bounds__(256) void convert_bf16(
    const float* __restrict__ in, u16* __restrict__ out) {
  int i = blockIdx.x * 256 + threadIdx.x;
  const float4* p = (const float4*)in + (size_t)i * 2;
  float4 a = p[0], b = p[1];
  u16x8 r;
  r[0] = f2bf(a.x); r[1] = f2bf(a.y); r[2] = f2bf(a.z); r[3] = f2bf(a.w);
  r[4] = f2bf(b.x); r[5] = f2bf(b.y); r[6] = f2bf(b.z); r[7] = f2bf(b.w);
  *((u16x8*)out + i) = r;
}

// -------- gating: fp64 logits, softmax, top-2 -> ws; also emits xbf ----------
__global__ __launch_bounds__(256) void gate_kernel(
    const float* __restrict__ x, const float* __restrict__ gW,
    const float* __restrict__ gb, float* __restrict__ probs,
    int* __restrict__ top2, u16* __restrict__ xbf) {
  const int wave = threadIdx.x >> 6;
  const int lane = threadIdx.x & 63;
  const int t = blockIdx.x * 4 + wave;

  const float4* xrow = (const float4*)(x + (size_t)t * DIM);
  double acc[NEXP];
#pragma unroll
  for (int e = 0; e < NEXP; ++e) acc[e] = 0.0;

#pragma unroll
  for (int c = 0; c < 4; ++c) {
    int idx = c * 64 + lane;          // float4 index; elems 4*idx..4*idx+3
    float4 xv = xrow[idx];
    u16x4 bv;
    bv[0] = f2bf(xv.x); bv[1] = f2bf(xv.y); bv[2] = f2bf(xv.z); bv[3] = f2bf(xv.w);
    *(u16x4*)(xbf + (size_t)t * DIM + 4 * idx) = bv;   // fused convert_x
#pragma unroll
    for (int e = 0; e < NEXP; ++e) {
      float4 wv = ((const float4*)(gW + (size_t)e * DIM))[idx];
      acc[e] += (double)xv.x * wv.x + (double)xv.y * wv.y +
                (double)xv.z * wv.z + (double)xv.w * wv.w;
    }
  }
#pragma unroll
  for (int e = 0; e < NEXP; ++e) {
    double v = acc[e];
#pragma unroll
    for (int off = 32; off > 0; off >>= 1) v += __shfl_down(v, off);
    acc[e] = v;
  }

  if (lane == 0) {
    double logits[NEXP];
#pragma unroll
    for (int e = 0; e < NEXP; ++e) logits[e] = acc[e] + (double)gb[e];
    double m = logits[0];
#pragma unroll
    for (int e = 1; e < NEXP; ++e) m = fmax(m, logits[e]);
    double p[NEXP], s = 0.0;
#pragma unroll
    for (int e = 0; e < NEXP; ++e) { p[e] = exp(logits[e] - m); s += p[e]; }
#pragma unroll
    for (int e = 0; e < NEXP; ++e) p[e] /= s;

    int i1 = 0;
#pragma unroll
    for (int e = 1; e < NEXP; ++e) if (p[e] > p[i1]) i1 = e;
    int i2 = (i1 == 0) ? 1 : 0;
#pragma unroll
    for (int e = 0; e < NEXP; ++e) {
      if (e != i1 && p[e] > p[i2]) i2 = e;
    }

#pragma unroll
    for (int e = 0; e < NEXP; ++e) probs[(size_t)t * NEXP + e] = (float)p[e];
    top2[t] = i1 | (i2 << 4);
  }
}

// ------- route: per-expert stable compaction (ballot prefix) + fp64 variance -
__global__ __launch_bounds__(256) void route_kernel(
    const float* __restrict__ probs, const int* __restrict__ top2,
    int* __restrict__ counts, int* __restrict__ lists,
    float* __restrict__ var_out) {
  const int e = blockIdx.x;
  const int tid = threadIdx.x;
  const int lane = tid & 63;
  const int wave = tid >> 6;

  __shared__ int wsum[4];
  __shared__ double ds[4], dq[4];

  double s = 0.0, q = 0.0;
  int base = 0;

  for (int c = 0; c < NTOK / 256; ++c) {
    int t = c * 256 + tid;
    float p = probs[(size_t)t * NEXP + e];
    s += (double)p;
    q += (double)p * (double)p;

    int m = top2[t];
    bool f = ((m & 15) == e) || (((m >> 4) & 15) == e);
    unsigned long long bal = __ballot(f);
    int before = __popcll(bal & ((1ull << lane) - 1ull));
    if (lane == 0) wsum[wave] = __popcll(bal);
    __syncthreads();
    int woff = 0;
#pragma unroll
    for (int w = 0; w < 4; ++w) if (w < wave) woff += wsum[w];
    int ctotal = wsum[0] + wsum[1] + wsum[2] + wsum[3];
    if (f) lists[e * NTOK + base + woff + before] = t;
    base += ctotal;
    __syncthreads();
  }
  if (tid == 0) counts[e] = base;

#pragma unroll
  for (int off = 32; off > 0; off >>= 1) {
    s += __shfl_down(s, off);
    q += __shfl_down(q, off);
  }
  if (lane == 0) { ds[wave] = s; dq[wave] = q; }
  __syncthreads();
  if (tid == 0) {
    double S = ds[0] + ds[1] + ds[2] + ds[3];
    double Q = dq[0] + dq[1] + dq[2] + dq[3];
    var_out[e] = (float)((Q - S * S / (double)NTOK) / (double)(NTOK - 1));
  }
}

// ------ gathered expert GEMM: dbuf + prefetch-1, global_load_lds, swizzle ----
// LDS tile (A and B, per buffer): logical [128 rows][64 cols] bf16 row-major,
// 16B-chunk swizzle stored_c16 = c16 ^ (row&7). global_load_lds writes LDS
// linearly; the global source carries the inverse (same) XOR.
__global__ __launch_bounds__(256, 2) void expert_gemm(
    const u16* __restrict__ xbf, const u16* __restrict__ wbf,
    const float* __restrict__ eb, const int* __restrict__ counts,
    const int* __restrict__ lists, float* __restrict__ out) {
  __shared__ u16 As[2][BM * BK];   // 2 x 16 KB
  __shared__ u16 Bs[2][BN * BK];   // 2 x 16 KB
  __shared__ int tok[BM];

  const int bid = blockIdx.x;
  const int e  = bid >> 9;          // 512 blocks/expert: 32 rb x 16 cb
  const int rb = (bid >> 4) & 31;
  const int cb = bid & 15;
  const int cnt = counts[e];
  if (rb * BM >= cnt) return;

  const int tid  = threadIdx.x;
  const int wave = tid >> 6;
  const int lane = tid & 63;

  if (tid < BM) {
    int gi = rb * BM + tid;
    tok[tid] = (gi < cnt) ? lists[e * NTOK + gi] : -1;
  }
  __syncthreads();

  // ---- staging precompute: 4 A-issues + 4 B-issues of 16B per thread ----
  const u16* asrc[4];
  const u16* bsrc[4];
  int ldsoff[4];                                  // u16 units, same for A and B
#pragma unroll
  for (int j = 0; j < 4; ++j) {
    const int idx  = (j * 4 + wave) * 64 + lane;  // 16B-chunk index in [0,1024)
    const int row  = idx >> 3;
    const int c16  = (idx & 7) ^ (row & 7);       // inverse swizzle on source
    int tr = tok[row]; if (tr < 0) tr = 0;        // clamped; row discarded later
    asrc[j] = xbf + (size_t)tr * DIM + c16 * 8;
    bsrc[j] = wbf + ((size_t)e * HID + (size_t)cb * BN + row) * DIM + c16 * 8;
    ldsoff[j] = (j * 4 + wave) * 512;             // wave-uniform base
  }

#define STAGE(buf, k0)                                                   \
  do {                                                                   \
    _Pragma("unroll")                                                    \
    for (int j = 0; j < 4; ++j) gload16(&As[buf][ldsoff[j]], asrc[j] + (k0)); \
    _Pragma("unroll")                                                    \
    for (int j = 0; j < 4; ++j) gload16(&Bs[buf][ldsoff[j]], bsrc[j] + (k0)); \
  } while (0)

  // ---- fragment read addresses (swizzled) ----
  const int wm = (wave >> 1) * 64;
  const int wn = (wave & 1) * 64;
  const int lr = lane & 15;
  const int hk = lane >> 4;        // k-group 0..3

  f32x4 acc[4][4];
#pragma unroll
  for (int m = 0; m < 4; ++m)
#pragma unroll
    for (int n = 0; n < 4; ++n) acc[m][n] = (f32x4)(0.0f);

  // prologue: stage K-tile 0 into buf 0
  STAGE(0, 0);
  __syncthreads();                 // drains vmcnt(0) + barrier

  int cur = 0;
  for (int kt = 0; kt < DIM / BK; ++kt) {
    if (kt + 1 < DIM / BK) STAGE(cur ^ 1, (kt + 1) * BK);  // prefetch next

    bf16x8 fa[2][4], fb[2][4];
#pragma unroll
    for (int kk = 0; kk < 2; ++kk) {
#pragma unroll
      for (int m = 0; m < 4; ++m) {
        const int row = wm + m * 16 + lr;
        const int c16 = (kk * 4 + hk) ^ (row & 7);
        fa[kk][m] = *(const bf16x8*)&As[cur][row * 64 + c16 * 8];
      }
#pragma unroll
      for (int n = 0; n < 4; ++n) {
        const int row = wn + n * 16 + lr;
        const int c16 = (kk * 4 + hk) ^ (row & 7);
        fb[kk][n] = *(const bf16x8*)&Bs[cur][row * 64 + c16 * 8];
      }
    }

#pragma unroll
    for (int kk = 0; kk < 2; ++kk)
#pragma unroll
      for (int m = 0; m < 4; ++m)
#pragma unroll
        for (int n = 0; n < 4; ++n)
          acc[m][n] = __builtin_amdgcn_mfma_f32_16x16x32_bf16(
              fa[kk][m], fb[kk][n], acc[m][n], 0, 0, 0);

    __syncthreads();               // one vmcnt(0)-drain + barrier per K-tile
    cur ^= 1;
  }
#undef STAGE

  // epilogue: out[token, h] += 0.5*(dot + bias)  (2 commutative adds/elem)
#pragma unroll
  for (int n = 0; n < 4; ++n) {
    const int hcol = cb * BN + wn + n * 16 + lr;
    const float bias = eb[e * HID + hcol];
#pragma unroll
    for (int m = 0; m < 4; ++m) {
#pragma unroll
      for (int i = 0; i < 4; ++i) {
        int rloc = wm + m * 16 + hk * 4 + i;   // C/D: row=(lane>>4)*4+i
        int tr = tok[rloc];
        if (tr >= 0)
          atomicAdd(&out[(size_t)tr * HID + hcol], 0.5f * (acc[m][n][i] + bias));
      }
    }
  }
}

extern "C" void kernel_launch(void* const* d_in, const int* in_sizes, int n_in,
                              void* d_out, int out_size, void* d_ws, size_t ws_size,
                              hipStream_t stream) {
  const float* x  = (const float*)d_in[0];   // [4096,1024]
  const float* gW = (const float*)d_in[1];   // [8,1024]
  const float* gb = (const float*)d_in[2];   // [8]
  const float* eW = (const float*)d_in[3];   // [8,2048,1024]
  const float* eb = (const float*)d_in[4];   // [8,2048]

  float* out = (float*)d_out;
  float* var_out = out + (size_t)NTOK * HID;

  // ws layout
  char* ws = (char*)d_ws;
  int*   counts = (int*)ws;                                   // 32 B
  int*   lists  = (int*)(ws + 1024);                          // 128 KB
  float* probs  = (float*)(ws + 1024 + 131072);               // 128 KB
  int*   top2   = (int*)(ws + 1024 + 2 * 131072);             // 16 KB
  u16*   xbf    = (u16*)(ws + 1024 + 2 * 131072 + 16384);     // 8 MB
  u16*   wbf    = (u16*)((char*)xbf + (size_t)NTOK * DIM * 2);// 32 MB

  hipMemsetAsync(d_out, 0, (size_t)out_size * sizeof(float), stream);

  convert_bf16<<<(NEXP * HID * DIM) / (256 * 8), 256, 0, stream>>>(eW, wbf);
  gate_kernel<<<NTOK / 4, 256, 0, stream>>>(x, gW, gb, probs, top2, xbf);
  route_kernel<<<NEXP, 256, 0, stream>>>(probs, top2, counts, lists, var_out);
  expert_gemm<<<NEXP * (NTOK / BM) * (HID / BN), 256, 0, stream>>>(
      xbf, wbf, eb, counts, lists, out);
}